// Round 10
// baseline (276234.448 us; speedup 1.0000x reference)
//
#include <hip/hip_runtime.h>

constexpr int   NROWS = 65536;
constexpr int   NK    = 1024;
constexpr float PAv   = 1.0f / 65536.0f;
constexpr float PBv   = 1.0f / 1024.0f;
constexpr float FI    = 1.0f / 1.1f;          // GAMMA/(GAMMA+eps)
constexpr float NEG_INV_EPS = -10.0f;         // -1/eps
constexpr float STOPERR2 = 1e-12f;            // (1e-6)^2 on squared 2-norm
constexpr int   MAXIT = 1000;

// ---------------- per-iteration step kernel (non-cooperative) --------------
// Kernel boundary = grid barrier (cross-XCD visibility guaranteed between
// dependent dispatches on one stream). 2048 x 256: the streaming shape this
// chip reaches ~6.3 TB/s with. Coop launch (1 blk/CU, 25% occupancy) pinned
// BW at ~2 TB/s regardless of per-wave MLP (r1-r8 evidence).
constexpr int PA_BLOCKS  = 2048;
constexpr int PA_THREADS = 256;
constexpr int PA_WAVES   = PA_THREADS / 64;                  // 4
constexpr int PA_RPW     = NROWS / (PA_BLOCKS * PA_WAVES);   // 8 rows per wave

__global__ __launch_bounds__(PA_THREADS, 6)   // VGPR cap ~85, 24 waves/CU
void ssk_step(const float* __restrict__ P, float* __restrict__ csp /*[4][NK]*/,
              float* __restrict__ b_ring /*[2][NK]*/, float* __restrict__ b_glob,
              int* __restrict__ flag, const int t)
{
  if (flag[0]) return;                        // converged in an earlier kernel

  __shared__ float b_lds[NK];
  __shared__ float wcs[PA_WAVES][NK];         // 16 KiB
  __shared__ float redsh[PA_WAVES];

  const int tid  = threadIdx.x;
  const int wave = tid >> 6;
  const int lane = tid & 63;
  const int bid  = blockIdx.x;

  const float* __restrict__ cs_prev = csp + (size_t)((t + 3) & 3) * NK;
  float* __restrict__ cs_cur  = csp + (size_t)(t & 3) * NK;
  float* __restrict__ cs_next = csp + (size_t)((t + 1) & 3) * NK;

  // b_t from cs_{t-1} (4 columns per thread), redundantly & bit-identically
  // in every block. t==0: b_0 = 1/K exactly (no cs read -> no init kernel).
  float bn[4];
  float e2 = 0.0f;
  #pragma unroll
  for (int j = 0; j < 4; ++j) {
    const int c = tid * 4 + j;
    bn[j] = (t == 0) ? PBv : powf(PBv / fmaxf(cs_prev[c], 1e-12f), FI);
    b_lds[c] = bn[j];
  }
  if (t >= 1) {                               // err_t = ||b_t - b_{t-1}||^2
    const float* __restrict__ bp = b_ring + (size_t)((t + 1) & 1) * NK;
    #pragma unroll
    for (int j = 0; j < 4; ++j) {
      const float d = bn[j] - bp[tid * 4 + j];
      e2 = fmaf(d, d, e2);
    }
    #pragma unroll
    for (int off = 32; off; off >>= 1) e2 += __shfl_xor(e2, off);
    if (lane == 0) redsh[wave] = e2;
  }
  __syncthreads();

  float err = 0.0f;
  if (t >= 1) err = redsh[0] + redsh[1] + redsh[2] + redsh[3];  // uniform bits
  const bool stop = (t >= 1 && err <= STOPERR2) || (t == MAXIT);
  if (stop) {
    // publish final b (identical redundant writes) and freeze later kernels
    #pragma unroll
    for (int j = 0; j < 4; ++j) b_glob[tid * 4 + j] = bn[j];
    if (tid == 0) flag[0] = 1;
    return;
  }

  if (bid == 0) {                             // publish b_t for kernel t+1's err
    float* __restrict__ bw = b_ring + (size_t)(t & 1) * NK;
    #pragma unroll
    for (int j = 0; j < 4; ++j) bw[tid * 4 + j] = bn[j];
  }
  // zero kernel t+1's accumulator slot, EXACTLY NK entries (r9 bug: wrote
  // 4096 entries, wiping neighboring slots incl. cs_cur mid-accumulation).
  // Slot (t+1)&3's last reader was kernel t-2 (as its cs_prev): two kernel
  // boundaries ago -> safe to zero here.
  if (bid < NK / 4 && tid < 4) cs_next[bid * 4 + tid] = 0.0f;

  // lane's 16 columns: 256*k + 4*lane + j  (proven layout)
  float bb[16];
  #pragma unroll
  for (int k = 0; k < 4; ++k)
    #pragma unroll
    for (int j = 0; j < 4; ++j)
      bb[4 * k + j] = b_lds[256 * k + 4 * lane + j];

  float acc[16];
  #pragma unroll
  for (int v = 0; v < 16; ++v) acc[v] = 0.0f;

  const int row0 = bid * (PA_WAVES * PA_RPW) + wave * PA_RPW;
  for (int r = 0; r < PA_RPW; r += 2) {       // 2-row batch (r5-proven order)
    const float4* rpA = reinterpret_cast<const float4*>(P) + (size_t)(row0 + r)     * (NK / 4);
    const float4* rpB = reinterpret_cast<const float4*>(P) + (size_t)(row0 + r + 1) * (NK / 4);
    float4 va[4], vb[4];
    #pragma unroll
    for (int k = 0; k < 4; ++k) { va[k] = rpA[(k << 6) + lane]; vb[k] = rpB[(k << 6) + lane]; }
    #pragma unroll
    for (int k = 0; k < 4; ++k) {
      va[k].x = __expf(va[k].x * NEG_INV_EPS);
      va[k].y = __expf(va[k].y * NEG_INV_EPS);
      va[k].z = __expf(va[k].z * NEG_INV_EPS);
      va[k].w = __expf(va[k].w * NEG_INV_EPS);
      vb[k].x = __expf(vb[k].x * NEG_INV_EPS);
      vb[k].y = __expf(vb[k].y * NEG_INV_EPS);
      vb[k].z = __expf(vb[k].z * NEG_INV_EPS);
      vb[k].w = __expf(vb[k].w * NEG_INV_EPS);
    }
    float dA = 0.f, dB = 0.f;
    #pragma unroll
    for (int k = 0; k < 4; ++k) {
      dA = fmaf(va[k].x, bb[4*k+0], dA);
      dA = fmaf(va[k].y, bb[4*k+1], dA);
      dA = fmaf(va[k].z, bb[4*k+2], dA);
      dA = fmaf(va[k].w, bb[4*k+3], dA);
      dB = fmaf(vb[k].x, bb[4*k+0], dB);
      dB = fmaf(vb[k].y, bb[4*k+1], dB);
      dB = fmaf(vb[k].z, bb[4*k+2], dB);
      dB = fmaf(vb[k].w, bb[4*k+3], dB);
    }
    #pragma unroll
    for (int off = 32; off; off >>= 1) {
      dA += __shfl_xor(dA, off);
      dB += __shfl_xor(dB, off);
    }
    const float aA = PAv / fmaxf(dA, 1e-12f);
    const float aB = PAv / fmaxf(dB, 1e-12f);
    #pragma unroll
    for (int k = 0; k < 4; ++k) {
      acc[4*k+0] = fmaf(aA, va[k].x, acc[4*k+0]);
      acc[4*k+1] = fmaf(aA, va[k].y, acc[4*k+1]);
      acc[4*k+2] = fmaf(aA, va[k].z, acc[4*k+2]);
      acc[4*k+3] = fmaf(aA, va[k].w, acc[4*k+3]);
      acc[4*k+0] = fmaf(aB, vb[k].x, acc[4*k+0]);
      acc[4*k+1] = fmaf(aB, vb[k].y, acc[4*k+1]);
      acc[4*k+2] = fmaf(aB, vb[k].z, acc[4*k+2]);
      acc[4*k+3] = fmaf(aB, vb[k].w, acc[4*k+3]);
    }
  }

  // block-level column reduction, one global atomic per column per block
  #pragma unroll
  for (int k = 0; k < 4; ++k)
    #pragma unroll
    for (int j = 0; j < 4; ++j)
      wcs[wave][256 * k + 4 * lane + j] = acc[4 * k + j];
  __syncthreads();
  #pragma unroll
  for (int j = 0; j < 4; ++j) {
    const int c = tid * 4 + j;
    const float s = wcs[0][c] + wcs[1][c] + wcs[2][c] + wcs[3][c];
    atomicAdd(&cs_cur[c], s);
  }
}

// ---------------- finalize: OT_plan + partial reductions (proven) ----------
constexpr int FN_BLOCKS  = 2048;
constexpr int FN_THREADS = 256;
constexpr int FN_WAVES   = FN_THREADS / 64;                  // 4
constexpr int FN_RPW     = NROWS / (FN_BLOCKS * FN_WAVES);   // 8

__global__ __launch_bounds__(FN_THREADS)
void ssk_finalize_kernel(const float* __restrict__ P, const float* __restrict__ b_glob,
                         float* __restrict__ out, float* __restrict__ wsum,
                         float* __restrict__ loss_part)
{
  __shared__ float b_sh[NK];
  __shared__ float wave_w[FN_WAVES][NK];
  __shared__ float red[FN_WAVES];

  const int tid  = threadIdx.x;
  const int wave = tid >> 6;
  const int lane = tid & 63;

  #pragma unroll
  for (int i = 0; i < 4; ++i) b_sh[tid + 256 * i] = b_glob[tid + 256 * i];
  __syncthreads();

  float bb[16];
  #pragma unroll
  for (int k = 0; k < 4; ++k)
    #pragma unroll
    for (int j = 0; j < 4; ++j)
      bb[4 * k + j] = b_sh[256 * k + 4 * lane + j];

  float wacc[16];
  #pragma unroll
  for (int v = 0; v < 16; ++v) wacc[v] = 0.0f;
  float lacc = 0.0f;

  const int row0 = (blockIdx.x * FN_WAVES + wave) * FN_RPW;
  float4* out4 = reinterpret_cast<float4*>(out);

  for (int r = 0; r < FN_RPW; ++r) {
    const size_t row = (size_t)(row0 + r);
    const float4* rp = reinterpret_cast<const float4*>(P) + row * (NK / 4);
    float4 pv[4];
    float Q[16];
    float dot = 0.0f;
    #pragma unroll
    for (int k = 0; k < 4; ++k) {
      pv[k] = rp[(k << 6) + lane];
      Q[4*k+0] = __expf(pv[k].x * NEG_INV_EPS);
      Q[4*k+1] = __expf(pv[k].y * NEG_INV_EPS);
      Q[4*k+2] = __expf(pv[k].z * NEG_INV_EPS);
      Q[4*k+3] = __expf(pv[k].w * NEG_INV_EPS);
      dot = fmaf(Q[4*k+0], bb[4*k+0], dot);
      dot = fmaf(Q[4*k+1], bb[4*k+1], dot);
      dot = fmaf(Q[4*k+2], bb[4*k+2], dot);
      dot = fmaf(Q[4*k+3], bb[4*k+3], dot);
    }
    #pragma unroll
    for (int off = 32; off; off >>= 1) dot += __shfl_xor(dot, off);
    const float s = 1.0f / fmaxf(dot, 1e-12f);    // N * a_i  (N*Pa = 1)
    #pragma unroll
    for (int k = 0; k < 4; ++k) {
      float4 o;
      o.x = s * Q[4*k+0] * bb[4*k+0];
      o.y = s * Q[4*k+1] * bb[4*k+1];
      o.z = s * Q[4*k+2] * bb[4*k+2];
      o.w = s * Q[4*k+3] * bb[4*k+3];
      out4[row * (NK / 4) + (k << 6) + lane] = o;
      lacc = fmaf(o.x, pv[k].x, lacc);
      lacc = fmaf(o.y, pv[k].y, lacc);
      lacc = fmaf(o.z, pv[k].z, lacc);
      lacc = fmaf(o.w, pv[k].w, lacc);
      wacc[4*k+0] += o.x; wacc[4*k+1] += o.y; wacc[4*k+2] += o.z; wacc[4*k+3] += o.w;
    }
  }

  #pragma unroll
  for (int k = 0; k < 4; ++k)
    #pragma unroll
    for (int j = 0; j < 4; ++j)
      wave_w[wave][256 * k + 4 * lane + j] = wacc[4 * k + j];
  __syncthreads();
  #pragma unroll
  for (int i = 0; i < 4; ++i) {
    const int c = tid + 256 * i;
    float s2 = wave_w[0][c] + wave_w[1][c] + wave_w[2][c] + wave_w[3][c];
    atomicAdd(&wsum[c], s2);
  }

  #pragma unroll
  for (int off = 32; off; off >>= 1) lacc += __shfl_xor(lacc, off);
  if (lane == 0) red[wave] = lacc;
  __syncthreads();
  if (tid == 0) loss_part[blockIdx.x] = red[0] + red[1] + red[2] + red[3];
}

// ---------------- finish: scalars ----------------
__device__ __forceinline__ float ssk_block_sum_1024(float v, float* red, int wave, int lane)
{
  #pragma unroll
  for (int off = 32; off; off >>= 1) v += __shfl_xor(v, off);
  __syncthreads();
  if (lane == 0) red[wave] = v;
  __syncthreads();
  float t = 0.0f;
  #pragma unroll
  for (int w = 0; w < 16; ++w) t += red[w];
  return t;
}

__global__ __launch_bounds__(1024)
void ssk_finish_kernel(const float* __restrict__ wsum, const float* __restrict__ loss_part,
                       float* __restrict__ out)
{
  __shared__ float red[16];
  const int tid = threadIdx.x, wave = tid >> 6, lane = tid & 63;

  float l  = loss_part[tid] + loss_part[tid + 1024];
  float lt = ssk_block_sum_1024(l, red, wave, lane);

  float wm = wsum[tid] * (1.0f / (float)NROWS);
  float sw = ssk_block_sum_1024(wm, red, wave, lane);
  float wn = wm / (sw + 1e-8f);
  float v  = PBv * (logf(PBv) - logf(wn + 1e-7f));
  float rg = ssk_block_sum_1024(v, red, wave, lane);

  if (tid == 0) {
    out[(size_t)NROWS * NK]     = lt / (float)NROWS;  // ot_loss
    out[(size_t)NROWS * NK + 1] = rg;                 // reg
  }
}

// ---------------- launch ----------------
extern "C" void kernel_launch(void* const* d_in, const int* in_sizes, int n_in,
                              void* d_out, int out_size, void* d_ws, size_t ws_size,
                              hipStream_t stream)
{
  const float* P = (const float*)d_in[0];
  float* out = (float*)d_out;
  float* ws  = (float*)d_ws;

  float* csp       = ws;             // [4][1024]
  float* wsum      = ws + 4096;      // [1024]
  int*   flag      = (int*)(ws + 5120);  // own line (pad to 5376)
  float* b_ring    = ws + 5376;      // [2][1024]
  float* b_glob    = ws + 7424;      // [1024]
  float* loss_part = ws + 8448;      // [2048]

  // zero csp (slots 0/1 are kernels 0/1's accumulators), wsum, flag
  hipMemsetAsync(ws, 0, 5376 * sizeof(float), stream);

  for (int t = 0; t <= MAXIT; ++t) {     // t==MAXIT: extractor-only kernel
    ssk_step<<<dim3(PA_BLOCKS), dim3(PA_THREADS), 0, stream>>>(
        P, csp, b_ring, b_glob, flag, t);
  }

  ssk_finalize_kernel<<<dim3(FN_BLOCKS), dim3(FN_THREADS), 0, stream>>>(
      P, b_glob, out, wsum, loss_part);
  ssk_finish_kernel<<<dim3(1), dim3(1024), 0, stream>>>(wsum, loss_part, out);
}

// Round 11
// 52795.972 us; speedup vs baseline: 5.2321x; 5.2321x over previous
//
#include <hip/hip_runtime.h>
#include <hip/hip_cooperative_groups.h>

namespace cg = cooperative_groups;

constexpr int   NROWS = 65536;
constexpr int   NK    = 1024;
constexpr float PAv   = 1.0f / 65536.0f;
constexpr float PBv   = 1.0f / 1024.0f;
constexpr float FI    = 1.0f / 1.1f;          // GAMMA/(GAMMA+eps)
constexpr float NEG_INV_EPS = -10.0f;         // -1/eps
constexpr float STOPERR2 = 1e-12f;            // (1e-6)^2 on squared 2-norm
constexpr int   MAXIT = 1000;
constexpr float INVS  = 1.0f / 65535.0f;      // u16 fixed-point decode scale

// ---------------- Q conversion: P f32 -> Q u16 fixed-point ----------------
// Q = exp(-10P) in [4.5e-5, 1]; u16 abs quantization err <= 7.6e-6 -> the
// iteration map's fixed point shifts ~1e-5 relative (48x amplification of a
// 3e-7 per-iter perturbation) -> OT error ~2e-7, below the bf16 output floor.
__global__ __launch_bounds__(256)
void q_conv_kernel(const float* __restrict__ P, uint4* __restrict__ Qb)
{
  const size_t total8 = (size_t)NROWS * NK / 8;
  for (size_t i = (size_t)blockIdx.x * blockDim.x + threadIdx.x; i < total8;
       i += (size_t)gridDim.x * blockDim.x) {
    const float4* p4 = reinterpret_cast<const float4*>(P) + 2 * i;
    float4 a = p4[0], b = p4[1];
    unsigned int u0 = __float2uint_rn(__expf(a.x * NEG_INV_EPS) * 65535.0f);
    unsigned int u1 = __float2uint_rn(__expf(a.y * NEG_INV_EPS) * 65535.0f);
    unsigned int u2 = __float2uint_rn(__expf(a.z * NEG_INV_EPS) * 65535.0f);
    unsigned int u3 = __float2uint_rn(__expf(a.w * NEG_INV_EPS) * 65535.0f);
    unsigned int u4 = __float2uint_rn(__expf(b.x * NEG_INV_EPS) * 65535.0f);
    unsigned int u5 = __float2uint_rn(__expf(b.y * NEG_INV_EPS) * 65535.0f);
    unsigned int u6 = __float2uint_rn(__expf(b.z * NEG_INV_EPS) * 65535.0f);
    unsigned int u7 = __float2uint_rn(__expf(b.w * NEG_INV_EPS) * 65535.0f);
    uint4 o;
    o.x = u0 | (u1 << 16);
    o.y = u2 | (u3 << 16);
    o.z = u4 | (u5 << 16);
    o.w = u6 | (u7 << 16);
    Qb[i] = o;
  }
}

// ---------------- cooperative Sinkhorn iteration ----------------
// Geometry: 256 blocks x 512 threads (proven r5/r7; >256 coop blocks REJECTED
// on HW r2/r3). NGRP=4 split accumulators cut per-address atomic contention
// 256 -> 64 (r10 evidence: 2048-way contention cost ~300+ us/iter).
constexpr int IT_BLOCKS  = 256;
constexpr int IT_THREADS = 512;
constexpr int IT_WAVES   = IT_THREADS / 64;                 // 8
constexpr int IT_RPW     = NROWS / (IT_BLOCKS * IT_WAVES);  // 32 rows per wave
constexpr int NGRP       = 4;

template<bool U16>
__global__ __launch_bounds__(IT_THREADS, 2)
void ssk_iter(const void* __restrict__ src, float* __restrict__ csp /*[4][NGRP][NK]*/,
              float* __restrict__ b_out)
{
  cg::grid_group grid = cg::this_grid();
  __shared__ float b_lds[NK];
  __shared__ float wave_cs[IT_WAVES][NK];   // 32 KiB
  __shared__ float redsh[IT_WAVES];
  __shared__ float err_sh;

  const int tid  = threadIdx.x;
  const int wave = tid >> 6;
  const int lane = tid & 63;
  const int bid  = blockIdx.x;
  const int grp  = bid & (NGRP - 1);
  const int row0 = (bid * IT_WAVES + wave) * IT_RPW;

  b_lds[tid] = PBv; b_lds[tid + 512] = PBv;   // b0 = 1/K
  __syncthreads();

  int it = 0;
  for (;;) {
    float* __restrict__ cs_cur = csp + (size_t)(it & 3) * (NGRP * NK);
    // slice-zero slot (it+2)&3: block bid zeros columns bid*4..+3 in all 4
    // groups (16 floats; grid-wide exactly NGRP*NK). Last readers of that
    // slot (Phase B, iter it-2) are TWO grid.syncs behind -> safe (r5-proven
    // ring discipline, r9's out-of-bounds bug corrected by construction).
    if (tid < 4 * NGRP) {
      float* z = csp + (size_t)((it + 2) & 3) * (NGRP * NK);
      z[(tid >> 2) * NK + bid * 4 + (tid & 3)] = 0.0f;
    }

    // lane's 16 columns: 256*k + 4*lane + j  (proven layout, 0 LDS conflicts)
    float bb[16];
    #pragma unroll
    for (int k = 0; k < 4; ++k)
      #pragma unroll
      for (int j = 0; j < 4; ++j)
        bb[4 * k + j] = b_lds[256 * k + 4 * lane + j];

    float acc[16];
    #pragma unroll
    for (int t = 0; t < 16; ++t) acc[t] = 0.0f;

    for (int r = 0; r < IT_RPW; r += 2) {     // 2-row batch (r5-proven shape)
      float4 va[4], vb[4];
      if constexpr (U16) {
        const uint2* rA = reinterpret_cast<const uint2*>(src)
                        + (size_t)(row0 + r) * (NK / 4);
        const uint2* rB = rA + (NK / 4);
        uint2 ua[4], ub[4];
        #pragma unroll
        for (int k = 0; k < 4; ++k) { ua[k] = rA[(k << 6) + lane]; ub[k] = rB[(k << 6) + lane]; }
        #pragma unroll
        for (int k = 0; k < 4; ++k) {         // u16x4 -> f32x4 (no exp!)
          va[k].x = (float)(ua[k].x & 0xffffu) * INVS;
          va[k].y = (float)(ua[k].x >> 16)     * INVS;
          va[k].z = (float)(ua[k].y & 0xffffu) * INVS;
          va[k].w = (float)(ua[k].y >> 16)     * INVS;
          vb[k].x = (float)(ub[k].x & 0xffffu) * INVS;
          vb[k].y = (float)(ub[k].x >> 16)     * INVS;
          vb[k].z = (float)(ub[k].y & 0xffffu) * INVS;
          vb[k].w = (float)(ub[k].y >> 16)     * INVS;
        }
      } else {
        const float4* rpA = reinterpret_cast<const float4*>(src) + (size_t)(row0 + r)     * (NK / 4);
        const float4* rpB = reinterpret_cast<const float4*>(src) + (size_t)(row0 + r + 1) * (NK / 4);
        #pragma unroll
        for (int k = 0; k < 4; ++k) { va[k] = rpA[(k << 6) + lane]; vb[k] = rpB[(k << 6) + lane]; }
        #pragma unroll
        for (int k = 0; k < 4; ++k) {
          va[k].x = __expf(va[k].x * NEG_INV_EPS);
          va[k].y = __expf(va[k].y * NEG_INV_EPS);
          va[k].z = __expf(va[k].z * NEG_INV_EPS);
          va[k].w = __expf(va[k].w * NEG_INV_EPS);
          vb[k].x = __expf(vb[k].x * NEG_INV_EPS);
          vb[k].y = __expf(vb[k].y * NEG_INV_EPS);
          vb[k].z = __expf(vb[k].z * NEG_INV_EPS);
          vb[k].w = __expf(vb[k].w * NEG_INV_EPS);
        }
      }
      float dA = 0.f, dB = 0.f;
      #pragma unroll
      for (int k = 0; k < 4; ++k) {
        dA = fmaf(va[k].x, bb[4*k+0], dA);
        dA = fmaf(va[k].y, bb[4*k+1], dA);
        dA = fmaf(va[k].z, bb[4*k+2], dA);
        dA = fmaf(va[k].w, bb[4*k+3], dA);
        dB = fmaf(vb[k].x, bb[4*k+0], dB);
        dB = fmaf(vb[k].y, bb[4*k+1], dB);
        dB = fmaf(vb[k].z, bb[4*k+2], dB);
        dB = fmaf(vb[k].w, bb[4*k+3], dB);
      }
      #pragma unroll
      for (int off = 32; off; off >>= 1) {
        dA += __shfl_xor(dA, off);
        dB += __shfl_xor(dB, off);
      }
      const float aA = PAv / fmaxf(dA, 1e-12f);
      const float aB = PAv / fmaxf(dB, 1e-12f);
      #pragma unroll
      for (int k = 0; k < 4; ++k) {
        acc[4*k+0] = fmaf(aA, va[k].x, acc[4*k+0]);
        acc[4*k+1] = fmaf(aA, va[k].y, acc[4*k+1]);
        acc[4*k+2] = fmaf(aA, va[k].z, acc[4*k+2]);
        acc[4*k+3] = fmaf(aA, va[k].w, acc[4*k+3]);
        acc[4*k+0] = fmaf(aB, vb[k].x, acc[4*k+0]);
        acc[4*k+1] = fmaf(aB, vb[k].y, acc[4*k+1]);
        acc[4*k+2] = fmaf(aB, vb[k].z, acc[4*k+2]);
        acc[4*k+3] = fmaf(aB, vb[k].w, acc[4*k+3]);
      }
    }

    // block-level column reduction, one atomic per column per block into the
    // block's contention group (64 adds/address instead of 256)
    #pragma unroll
    for (int k = 0; k < 4; ++k)
      #pragma unroll
      for (int j = 0; j < 4; ++j)
        wave_cs[wave][256 * k + 4 * lane + j] = acc[4 * k + j];
    __syncthreads();
    #pragma unroll
    for (int h = 0; h < 2; ++h) {
      const int c = tid + 512 * h;
      float s = 0.f;
      #pragma unroll
      for (int w = 0; w < IT_WAVES; ++w) s += wave_cs[w][c];
      atomicAdd(&cs_cur[grp * NK + c], s);
    }

    grid.sync();   // the only grid-wide sync per iteration

    // Phase B: every block redundantly (bit-identically) computes b_new + err
    // (fixed group order -> identical FP sums in every block)
    float c0 = 0.f, c1 = 0.f;
    #pragma unroll
    for (int g = 0; g < NGRP; ++g) {
      c0 += cs_cur[g * NK + tid];
      c1 += cs_cur[g * NK + tid + 512];
    }
    const float bn0 = powf(PBv / fmaxf(c0, 1e-12f), FI);
    const float bn1 = powf(PBv / fmaxf(c1, 1e-12f), FI);
    const float e0 = bn0 - b_lds[tid], e1 = bn1 - b_lds[tid + 512];
    float sq = e0 * e0 + e1 * e1;
    #pragma unroll
    for (int off = 32; off; off >>= 1) sq += __shfl_xor(sq, off);
    if (lane == 0) redsh[wave] = sq;
    __syncthreads();
    if (tid == 0) {
      float s = 0.f;
      #pragma unroll
      for (int w = 0; w < IT_WAVES; ++w) s += redsh[w];
      err_sh = s;
    }
    b_lds[tid] = bn0; b_lds[tid + 512] = bn1;  // own-index write
    ++it;
    __syncthreads();     // publishes err_sh and b_lds
    if (err_sh <= STOPERR2 || it >= MAXIT) break;
  }

  if (blockIdx.x == 0) { b_out[tid] = b_lds[tid]; b_out[tid + 512] = b_lds[tid + 512]; }
}

// ---------------- finalize: OT_plan + partial reductions (proven) ----------
constexpr int FN_BLOCKS  = 2048;
constexpr int FN_THREADS = 256;
constexpr int FN_WAVES   = FN_THREADS / 64;                  // 4
constexpr int FN_RPW     = NROWS / (FN_BLOCKS * FN_WAVES);   // 8

__global__ __launch_bounds__(FN_THREADS)
void ssk_finalize_kernel(const float* __restrict__ P, const float* __restrict__ b_glob,
                         float* __restrict__ out, float* __restrict__ wsum,
                         float* __restrict__ loss_part)
{
  __shared__ float b_sh[NK];
  __shared__ float wave_w[FN_WAVES][NK];
  __shared__ float red[FN_WAVES];

  const int tid  = threadIdx.x;
  const int wave = tid >> 6;
  const int lane = tid & 63;

  #pragma unroll
  for (int i = 0; i < 4; ++i) b_sh[tid + 256 * i] = b_glob[tid + 256 * i];
  __syncthreads();

  float bb[16];
  #pragma unroll
  for (int k = 0; k < 4; ++k)
    #pragma unroll
    for (int j = 0; j < 4; ++j)
      bb[4 * k + j] = b_sh[256 * k + 4 * lane + j];

  float wacc[16];
  #pragma unroll
  for (int t = 0; t < 16; ++t) wacc[t] = 0.0f;
  float lacc = 0.0f;

  const int row0 = (blockIdx.x * FN_WAVES + wave) * FN_RPW;
  float4* out4 = reinterpret_cast<float4*>(out);

  for (int r = 0; r < FN_RPW; ++r) {
    const size_t row = (size_t)(row0 + r);
    const float4* rp = reinterpret_cast<const float4*>(P) + row * (NK / 4);
    float4 pv[4];
    float Q[16];
    float dot = 0.0f;
    #pragma unroll
    for (int k = 0; k < 4; ++k) {
      pv[k] = rp[(k << 6) + lane];
      Q[4*k+0] = __expf(pv[k].x * NEG_INV_EPS);
      Q[4*k+1] = __expf(pv[k].y * NEG_INV_EPS);
      Q[4*k+2] = __expf(pv[k].z * NEG_INV_EPS);
      Q[4*k+3] = __expf(pv[k].w * NEG_INV_EPS);
      dot = fmaf(Q[4*k+0], bb[4*k+0], dot);
      dot = fmaf(Q[4*k+1], bb[4*k+1], dot);
      dot = fmaf(Q[4*k+2], bb[4*k+2], dot);
      dot = fmaf(Q[4*k+3], bb[4*k+3], dot);
    }
    #pragma unroll
    for (int off = 32; off; off >>= 1) dot += __shfl_xor(dot, off);
    const float s = 1.0f / fmaxf(dot, 1e-12f);    // N * a_i  (N*Pa = 1)
    #pragma unroll
    for (int k = 0; k < 4; ++k) {
      float4 o;
      o.x = s * Q[4*k+0] * bb[4*k+0];
      o.y = s * Q[4*k+1] * bb[4*k+1];
      o.z = s * Q[4*k+2] * bb[4*k+2];
      o.w = s * Q[4*k+3] * bb[4*k+3];
      out4[row * (NK / 4) + (k << 6) + lane] = o;
      lacc = fmaf(o.x, pv[k].x, lacc);
      lacc = fmaf(o.y, pv[k].y, lacc);
      lacc = fmaf(o.z, pv[k].z, lacc);
      lacc = fmaf(o.w, pv[k].w, lacc);
      wacc[4*k+0] += o.x; wacc[4*k+1] += o.y; wacc[4*k+2] += o.z; wacc[4*k+3] += o.w;
    }
  }

  #pragma unroll
  for (int k = 0; k < 4; ++k)
    #pragma unroll
    for (int j = 0; j < 4; ++j)
      wave_w[wave][256 * k + 4 * lane + j] = wacc[4 * k + j];
  __syncthreads();
  #pragma unroll
  for (int i = 0; i < 4; ++i) {
    const int c = tid + 256 * i;
    float s2 = wave_w[0][c] + wave_w[1][c] + wave_w[2][c] + wave_w[3][c];
    atomicAdd(&wsum[c], s2);
  }

  #pragma unroll
  for (int off = 32; off; off >>= 1) lacc += __shfl_xor(lacc, off);
  if (lane == 0) red[wave] = lacc;
  __syncthreads();
  if (tid == 0) loss_part[blockIdx.x] = red[0] + red[1] + red[2] + red[3];
}

// ---------------- finish: scalars ----------------
__device__ __forceinline__ float ssk_block_sum_1024(float v, float* red, int wave, int lane)
{
  #pragma unroll
  for (int off = 32; off; off >>= 1) v += __shfl_xor(v, off);
  __syncthreads();
  if (lane == 0) red[wave] = v;
  __syncthreads();
  float t = 0.0f;
  #pragma unroll
  for (int w = 0; w < 16; ++w) t += red[w];
  return t;
}

__global__ __launch_bounds__(1024)
void ssk_finish_kernel(const float* __restrict__ wsum, const float* __restrict__ loss_part,
                       float* __restrict__ out)
{
  __shared__ float red[16];
  const int tid = threadIdx.x, wave = tid >> 6, lane = tid & 63;

  float l  = loss_part[tid] + loss_part[tid + 1024];
  float lt = ssk_block_sum_1024(l, red, wave, lane);

  float wm = wsum[tid] * (1.0f / (float)NROWS);
  float sw = ssk_block_sum_1024(wm, red, wave, lane);
  float wn = wm / (sw + 1e-8f);
  float v  = PBv * (logf(PBv) - logf(wn + 1e-7f));
  float rg = ssk_block_sum_1024(v, red, wave, lane);

  if (tid == 0) {
    out[(size_t)NROWS * NK]     = lt / (float)NROWS;  // ot_loss
    out[(size_t)NROWS * NK + 1] = rg;                 // reg
  }
}

// ---------------- launch ----------------
extern "C" void kernel_launch(void* const* d_in, const int* in_sizes, int n_in,
                              void* d_out, int out_size, void* d_ws, size_t ws_size,
                              hipStream_t stream)
{
  const float* P = (const float*)d_in[0];
  float* out = (float*)d_out;
  float* ws  = (float*)d_ws;

  float* csp = ws;                                     // [4][NGRP][1024] = 64 KB
  // u16 Q cache right after csp; aux tail after the cache.
  const size_t QF   = (size_t)NROWS * NK / 2;          // u16 cache in float units
  const size_t need = (16384 + QF + 4096 + 2048) * sizeof(float);

  if (ws_size >= need) {
    unsigned short* qbuf = (unsigned short*)(ws + 16384);
    float* b_glob    = ws + 16384 + QF;
    float* wsum      = b_glob + 1024;
    float* loss_part = b_glob + 2048;

    hipMemsetAsync(csp, 0, 16384 * sizeof(float), stream);   // all 4 ring slots
    hipMemsetAsync(b_glob, 0, 2048 * sizeof(float), stream); // b_glob + wsum

    q_conv_kernel<<<dim3(2048), dim3(256), 0, stream>>>(P, (uint4*)qbuf);

    const void* src = qbuf;
    void (*fp)(const void*, float*, float*) = ssk_iter<true>;
    void* args[] = { (void*)&src, (void*)&csp, (void*)&b_glob };
    hipLaunchCooperativeKernel((void*)fp, dim3(IT_BLOCKS), dim3(IT_THREADS),
                               args, 0, stream);

    ssk_finalize_kernel<<<dim3(FN_BLOCKS), dim3(FN_THREADS), 0, stream>>>(
        P, b_glob, out, wsum, loss_part);
    ssk_finish_kernel<<<dim3(1), dim3(1024), 0, stream>>>(wsum, loss_part, out);
  } else {
    float* b_glob    = ws + 16384;
    float* wsum      = ws + 17408;
    float* loss_part = ws + 18432;

    hipMemsetAsync(ws, 0, 18432 * sizeof(float), stream);    // csp + b_glob + wsum

    const void* src = (const void*)P;
    void (*fp)(const void*, float*, float*) = ssk_iter<false>;
    void* args[] = { (void*)&src, (void*)&csp, (void*)&b_glob };
    hipLaunchCooperativeKernel((void*)fp, dim3(IT_BLOCKS), dim3(IT_THREADS),
                               args, 0, stream);

    ssk_finalize_kernel<<<dim3(FN_BLOCKS), dim3(FN_THREADS), 0, stream>>>(
        P, b_glob, out, wsum, loss_part);
    ssk_finish_kernel<<<dim3(1), dim3(1024), 0, stream>>>(wsum, loss_part, out);
  }
}

// Round 12
// 51365.002 us; speedup vs baseline: 5.3779x; 1.0279x over previous
//
#include <hip/hip_runtime.h>
#include <hip/hip_cooperative_groups.h>

namespace cg = cooperative_groups;

constexpr int   NROWS = 65536;
constexpr int   NK    = 1024;
constexpr float PAv   = 1.0f / 65536.0f;
constexpr float PBv   = 1.0f / 1024.0f;
constexpr float FI    = 1.0f / 1.1f;          // GAMMA/(GAMMA+eps)
constexpr float NEG_INV_EPS = -10.0f;         // -1/eps
constexpr float STOPERR2 = 1e-12f;            // (1e-6)^2 on squared 2-norm
constexpr int   MAXIT = 1000;
constexpr float INVS  = 1.0f / 65535.0f;      // u16 fixed-point decode scale
constexpr float BETA  = 0.87f;                // heavy-ball momentum
constexpr int   WARMUP = 8;                   // plain iters before momentum

// ---------------- Q conversion: P f32 -> Q u16 fixed-point (proven r11) ----
__global__ __launch_bounds__(256)
void q_conv_kernel(const float* __restrict__ P, uint4* __restrict__ Qb)
{
  const size_t total8 = (size_t)NROWS * NK / 8;
  for (size_t i = (size_t)blockIdx.x * blockDim.x + threadIdx.x; i < total8;
       i += (size_t)gridDim.x * blockDim.x) {
    const float4* p4 = reinterpret_cast<const float4*>(P) + 2 * i;
    float4 a = p4[0], b = p4[1];
    unsigned int u0 = __float2uint_rn(__expf(a.x * NEG_INV_EPS) * 65535.0f);
    unsigned int u1 = __float2uint_rn(__expf(a.y * NEG_INV_EPS) * 65535.0f);
    unsigned int u2 = __float2uint_rn(__expf(a.z * NEG_INV_EPS) * 65535.0f);
    unsigned int u3 = __float2uint_rn(__expf(a.w * NEG_INV_EPS) * 65535.0f);
    unsigned int u4 = __float2uint_rn(__expf(b.x * NEG_INV_EPS) * 65535.0f);
    unsigned int u5 = __float2uint_rn(__expf(b.y * NEG_INV_EPS) * 65535.0f);
    unsigned int u6 = __float2uint_rn(__expf(b.z * NEG_INV_EPS) * 65535.0f);
    unsigned int u7 = __float2uint_rn(__expf(b.w * NEG_INV_EPS) * 65535.0f);
    uint4 o;
    o.x = u0 | (u1 << 16);
    o.y = u2 | (u3 << 16);
    o.z = u4 | (u5 << 16);
    o.w = u6 | (u7 << 16);
    Qb[i] = o;
  }
}

// ---------------- cooperative Sinkhorn iteration (r11 + momentum) ----------
constexpr int IT_BLOCKS  = 256;
constexpr int IT_THREADS = 512;
constexpr int IT_WAVES   = IT_THREADS / 64;                 // 8
constexpr int IT_RPW     = NROWS / (IT_BLOCKS * IT_WAVES);  // 32 rows per wave
constexpr int NGRP       = 4;

template<bool U16>
__global__ __launch_bounds__(IT_THREADS, 2)
void ssk_iter(const void* __restrict__ src, float* __restrict__ csp /*[4][NGRP][NK]*/,
              float* __restrict__ b_out)
{
  cg::grid_group grid = cg::this_grid();
  __shared__ float b_lds[NK];
  __shared__ float wave_cs[IT_WAVES][NK];   // 32 KiB
  __shared__ float redsh[IT_WAVES];
  __shared__ float err_sh;

  const int tid  = threadIdx.x;
  const int wave = tid >> 6;
  const int lane = tid & 63;
  const int bid  = blockIdx.x;
  const int grp  = bid & (NGRP - 1);
  const int row0 = (bid * IT_WAVES + wave) * IT_RPW;

  // momentum state (thread-local: components tid and tid+512)
  float bc0 = PBv, bc1 = PBv;   // x_k
  float bp0 = PBv, bp1 = PBv;   // x_{k-1}
  b_lds[tid] = PBv; b_lds[tid + 512] = PBv;
  __syncthreads();

  int it = 0;
  for (;;) {
    float* __restrict__ cs_cur = csp + (size_t)(it & 3) * (NGRP * NK);
    // slice-zero slot (it+2)&3 (exact NGRP*NK cover; r5-proven ring)
    if (tid < 4 * NGRP) {
      float* z = csp + (size_t)((it + 2) & 3) * (NGRP * NK);
      z[(tid >> 2) * NK + bid * 4 + (tid & 3)] = 0.0f;
    }

    // lane's 16 columns: 256*k + 4*lane + j  (proven layout, 0 LDS conflicts)
    float bb[16];
    #pragma unroll
    for (int k = 0; k < 4; ++k)
      #pragma unroll
      for (int j = 0; j < 4; ++j)
        bb[4 * k + j] = b_lds[256 * k + 4 * lane + j];

    float acc[16];
    #pragma unroll
    for (int t = 0; t < 16; ++t) acc[t] = 0.0f;

    for (int r = 0; r < IT_RPW; r += 2) {     // 2-row batch (r5/r11-proven)
      float4 va[4], vb[4];
      if constexpr (U16) {
        const uint2* rA = reinterpret_cast<const uint2*>(src)
                        + (size_t)(row0 + r) * (NK / 4);
        const uint2* rB = rA + (NK / 4);
        uint2 ua[4], ub[4];
        #pragma unroll
        for (int k = 0; k < 4; ++k) { ua[k] = rA[(k << 6) + lane]; ub[k] = rB[(k << 6) + lane]; }
        #pragma unroll
        for (int k = 0; k < 4; ++k) {         // u16x4 -> f32x4 (no exp!)
          va[k].x = (float)(ua[k].x & 0xffffu) * INVS;
          va[k].y = (float)(ua[k].x >> 16)     * INVS;
          va[k].z = (float)(ua[k].y & 0xffffu) * INVS;
          va[k].w = (float)(ua[k].y >> 16)     * INVS;
          vb[k].x = (float)(ub[k].x & 0xffffu) * INVS;
          vb[k].y = (float)(ub[k].x >> 16)     * INVS;
          vb[k].z = (float)(ub[k].y & 0xffffu) * INVS;
          vb[k].w = (float)(ub[k].y >> 16)     * INVS;
        }
      } else {
        const float4* rpA = reinterpret_cast<const float4*>(src) + (size_t)(row0 + r)     * (NK / 4);
        const float4* rpB = reinterpret_cast<const float4*>(src) + (size_t)(row0 + r + 1) * (NK / 4);
        #pragma unroll
        for (int k = 0; k < 4; ++k) { va[k] = rpA[(k << 6) + lane]; vb[k] = rpB[(k << 6) + lane]; }
        #pragma unroll
        for (int k = 0; k < 4; ++k) {
          va[k].x = __expf(va[k].x * NEG_INV_EPS);
          va[k].y = __expf(va[k].y * NEG_INV_EPS);
          va[k].z = __expf(va[k].z * NEG_INV_EPS);
          va[k].w = __expf(va[k].w * NEG_INV_EPS);
          vb[k].x = __expf(vb[k].x * NEG_INV_EPS);
          vb[k].y = __expf(vb[k].y * NEG_INV_EPS);
          vb[k].z = __expf(vb[k].z * NEG_INV_EPS);
          vb[k].w = __expf(vb[k].w * NEG_INV_EPS);
        }
      }
      float dA = 0.f, dB = 0.f;
      #pragma unroll
      for (int k = 0; k < 4; ++k) {
        dA = fmaf(va[k].x, bb[4*k+0], dA);
        dA = fmaf(va[k].y, bb[4*k+1], dA);
        dA = fmaf(va[k].z, bb[4*k+2], dA);
        dA = fmaf(va[k].w, bb[4*k+3], dA);
        dB = fmaf(vb[k].x, bb[4*k+0], dB);
        dB = fmaf(vb[k].y, bb[4*k+1], dB);
        dB = fmaf(vb[k].z, bb[4*k+2], dB);
        dB = fmaf(vb[k].w, bb[4*k+3], dB);
      }
      #pragma unroll
      for (int off = 32; off; off >>= 1) {
        dA += __shfl_xor(dA, off);
        dB += __shfl_xor(dB, off);
      }
      const float aA = PAv / fmaxf(dA, 1e-12f);
      const float aB = PAv / fmaxf(dB, 1e-12f);
      #pragma unroll
      for (int k = 0; k < 4; ++k) {
        acc[4*k+0] = fmaf(aA, va[k].x, acc[4*k+0]);
        acc[4*k+1] = fmaf(aA, va[k].y, acc[4*k+1]);
        acc[4*k+2] = fmaf(aA, va[k].z, acc[4*k+2]);
        acc[4*k+3] = fmaf(aA, va[k].w, acc[4*k+3]);
        acc[4*k+0] = fmaf(aB, vb[k].x, acc[4*k+0]);
        acc[4*k+1] = fmaf(aB, vb[k].y, acc[4*k+1]);
        acc[4*k+2] = fmaf(aB, vb[k].z, acc[4*k+2]);
        acc[4*k+3] = fmaf(aB, vb[k].w, acc[4*k+3]);
      }
    }

    // block-level column reduction, one atomic per column per block (NGRP split)
    #pragma unroll
    for (int k = 0; k < 4; ++k)
      #pragma unroll
      for (int j = 0; j < 4; ++j)
        wave_cs[wave][256 * k + 4 * lane + j] = acc[4 * k + j];
    __syncthreads();
    #pragma unroll
    for (int h = 0; h < 2; ++h) {
      const int c = tid + 512 * h;
      float s = 0.f;
      #pragma unroll
      for (int w = 0; w < IT_WAVES; ++w) s += wave_cs[w][c];
      atomicAdd(&cs_cur[grp * NK + c], s);
    }

    grid.sync();   // the only grid-wide sync per iteration

    // Phase B: bn = F(x_k); plain-map residual for the stop test (exactly the
    // reference's guarantee); then heavy-ball x_{k+1} = bn + beta*(x_k - x_{k-1}).
    float c0 = 0.f, c1 = 0.f;
    #pragma unroll
    for (int g = 0; g < NGRP; ++g) {           // fixed order: bit-identical
      c0 += cs_cur[g * NK + tid];
      c1 += cs_cur[g * NK + tid + 512];
    }
    const float bn0 = powf(PBv / fmaxf(c0, 1e-12f), FI);
    const float bn1 = powf(PBv / fmaxf(c1, 1e-12f), FI);
    const float e0 = bn0 - bc0, e1 = bn1 - bc1;
    float sq = e0 * e0 + e1 * e1;
    #pragma unroll
    for (int off = 32; off; off >>= 1) sq += __shfl_xor(sq, off);
    if (lane == 0) redsh[wave] = sq;
    __syncthreads();
    if (tid == 0) {
      float s = 0.f;
      #pragma unroll
      for (int w = 0; w < IT_WAVES; ++w) s += redsh[w];
      err_sh = s;
    }
    __syncthreads();
    const float err = err_sh;
    ++it;
    const bool stop = (err <= STOPERR2) || (it >= MAXIT);

    float nx0, nx1;
    if (stop) {
      nx0 = bn0; nx1 = bn1;                   // publish the plain-map image
    } else {
      const float beta = (it <= WARMUP) ? 0.0f : BETA;
      nx0 = bn0 + beta * (bc0 - bp0);
      nx1 = bn1 + beta * (bc1 - bp1);
      nx0 = fmaxf(nx0, 0.125f * bn0);         // positivity floor
      nx1 = fmaxf(nx1, 0.125f * bn1);
    }
    bp0 = bc0; bp1 = bc1;
    bc0 = nx0; bc1 = nx1;
    b_lds[tid] = nx0; b_lds[tid + 512] = nx1; // own-index write
    __syncthreads();                          // publishes b_lds for next iter
    if (stop) break;
  }

  if (blockIdx.x == 0) { b_out[tid] = b_lds[tid]; b_out[tid + 512] = b_lds[tid + 512]; }
}

// ---------------- finalize: OT_plan + partial reductions (proven) ----------
constexpr int FN_BLOCKS  = 2048;
constexpr int FN_THREADS = 256;
constexpr int FN_WAVES   = FN_THREADS / 64;                  // 4
constexpr int FN_RPW     = NROWS / (FN_BLOCKS * FN_WAVES);   // 8

__global__ __launch_bounds__(FN_THREADS)
void ssk_finalize_kernel(const float* __restrict__ P, const float* __restrict__ b_glob,
                         float* __restrict__ out, float* __restrict__ wsum,
                         float* __restrict__ loss_part)
{
  __shared__ float b_sh[NK];
  __shared__ float wave_w[FN_WAVES][NK];
  __shared__ float red[FN_WAVES];

  const int tid  = threadIdx.x;
  const int wave = tid >> 6;
  const int lane = tid & 63;

  #pragma unroll
  for (int i = 0; i < 4; ++i) b_sh[tid + 256 * i] = b_glob[tid + 256 * i];
  __syncthreads();

  float bb[16];
  #pragma unroll
  for (int k = 0; k < 4; ++k)
    #pragma unroll
    for (int j = 0; j < 4; ++j)
      bb[4 * k + j] = b_sh[256 * k + 4 * lane + j];

  float wacc[16];
  #pragma unroll
  for (int t = 0; t < 16; ++t) wacc[t] = 0.0f;
  float lacc = 0.0f;

  const int row0 = (blockIdx.x * FN_WAVES + wave) * FN_RPW;
  float4* out4 = reinterpret_cast<float4*>(out);

  for (int r = 0; r < FN_RPW; ++r) {
    const size_t row = (size_t)(row0 + r);
    const float4* rp = reinterpret_cast<const float4*>(P) + row * (NK / 4);
    float4 pv[4];
    float Q[16];
    float dot = 0.0f;
    #pragma unroll
    for (int k = 0; k < 4; ++k) {
      pv[k] = rp[(k << 6) + lane];
      Q[4*k+0] = __expf(pv[k].x * NEG_INV_EPS);
      Q[4*k+1] = __expf(pv[k].y * NEG_INV_EPS);
      Q[4*k+2] = __expf(pv[k].z * NEG_INV_EPS);
      Q[4*k+3] = __expf(pv[k].w * NEG_INV_EPS);
      dot = fmaf(Q[4*k+0], bb[4*k+0], dot);
      dot = fmaf(Q[4*k+1], bb[4*k+1], dot);
      dot = fmaf(Q[4*k+2], bb[4*k+2], dot);
      dot = fmaf(Q[4*k+3], bb[4*k+3], dot);
    }
    #pragma unroll
    for (int off = 32; off; off >>= 1) dot += __shfl_xor(dot, off);
    const float s = 1.0f / fmaxf(dot, 1e-12f);    // N * a_i  (N*Pa = 1)
    #pragma unroll
    for (int k = 0; k < 4; ++k) {
      float4 o;
      o.x = s * Q[4*k+0] * bb[4*k+0];
      o.y = s * Q[4*k+1] * bb[4*k+1];
      o.z = s * Q[4*k+2] * bb[4*k+2];
      o.w = s * Q[4*k+3] * bb[4*k+3];
      out4[row * (NK / 4) + (k << 6) + lane] = o;
      lacc = fmaf(o.x, pv[k].x, lacc);
      lacc = fmaf(o.y, pv[k].y, lacc);
      lacc = fmaf(o.z, pv[k].z, lacc);
      lacc = fmaf(o.w, pv[k].w, lacc);
      wacc[4*k+0] += o.x; wacc[4*k+1] += o.y; wacc[4*k+2] += o.z; wacc[4*k+3] += o.w;
    }
  }

  #pragma unroll
  for (int k = 0; k < 4; ++k)
    #pragma unroll
    for (int j = 0; j < 4; ++j)
      wave_w[wave][256 * k + 4 * lane + j] = wacc[4 * k + j];
  __syncthreads();
  #pragma unroll
  for (int i = 0; i < 4; ++i) {
    const int c = tid + 256 * i;
    float s2 = wave_w[0][c] + wave_w[1][c] + wave_w[2][c] + wave_w[3][c];
    atomicAdd(&wsum[c], s2);
  }

  #pragma unroll
  for (int off = 32; off; off >>= 1) lacc += __shfl_xor(lacc, off);
  if (lane == 0) red[wave] = lacc;
  __syncthreads();
  if (tid == 0) loss_part[blockIdx.x] = red[0] + red[1] + red[2] + red[3];
}

// ---------------- finish: scalars ----------------
__device__ __forceinline__ float ssk_block_sum_1024(float v, float* red, int wave, int lane)
{
  #pragma unroll
  for (int off = 32; off; off >>= 1) v += __shfl_xor(v, off);
  __syncthreads();
  if (lane == 0) red[wave] = v;
  __syncthreads();
  float t = 0.0f;
  #pragma unroll
  for (int w = 0; w < 16; ++w) t += red[w];
  return t;
}

__global__ __launch_bounds__(1024)
void ssk_finish_kernel(const float* __restrict__ wsum, const float* __restrict__ loss_part,
                       float* __restrict__ out)
{
  __shared__ float red[16];
  const int tid = threadIdx.x, wave = tid >> 6, lane = tid & 63;

  float l  = loss_part[tid] + loss_part[tid + 1024];
  float lt = ssk_block_sum_1024(l, red, wave, lane);

  float wm = wsum[tid] * (1.0f / (float)NROWS);
  float sw = ssk_block_sum_1024(wm, red, wave, lane);
  float wn = wm / (sw + 1e-8f);
  float v  = PBv * (logf(PBv) - logf(wn + 1e-7f));
  float rg = ssk_block_sum_1024(v, red, wave, lane);

  if (tid == 0) {
    out[(size_t)NROWS * NK]     = lt / (float)NROWS;  // ot_loss
    out[(size_t)NROWS * NK + 1] = rg;                 // reg
  }
}

// ---------------- launch ----------------
extern "C" void kernel_launch(void* const* d_in, const int* in_sizes, int n_in,
                              void* d_out, int out_size, void* d_ws, size_t ws_size,
                              hipStream_t stream)
{
  const float* P = (const float*)d_in[0];
  float* out = (float*)d_out;
  float* ws  = (float*)d_ws;

  float* csp = ws;                                     // [4][NGRP][1024] = 64 KB
  const size_t QF   = (size_t)NROWS * NK / 2;          // u16 cache in float units
  const size_t need = (16384 + QF + 4096 + 2048) * sizeof(float);

  if (ws_size >= need) {
    unsigned short* qbuf = (unsigned short*)(ws + 16384);
    float* b_glob    = ws + 16384 + QF;
    float* wsum      = b_glob + 1024;
    float* loss_part = b_glob + 2048;

    hipMemsetAsync(csp, 0, 16384 * sizeof(float), stream);   // all 4 ring slots
    hipMemsetAsync(b_glob, 0, 2048 * sizeof(float), stream); // b_glob + wsum

    q_conv_kernel<<<dim3(2048), dim3(256), 0, stream>>>(P, (uint4*)qbuf);

    const void* src = qbuf;
    void (*fp)(const void*, float*, float*) = ssk_iter<true>;
    void* args[] = { (void*)&src, (void*)&csp, (void*)&b_glob };
    hipLaunchCooperativeKernel((void*)fp, dim3(IT_BLOCKS), dim3(IT_THREADS),
                               args, 0, stream);

    ssk_finalize_kernel<<<dim3(FN_BLOCKS), dim3(FN_THREADS), 0, stream>>>(
        P, b_glob, out, wsum, loss_part);
    ssk_finish_kernel<<<dim3(1), dim3(1024), 0, stream>>>(wsum, loss_part, out);
  } else {
    float* b_glob    = ws + 16384;
    float* wsum      = ws + 17408;
    float* loss_part = ws + 18432;

    hipMemsetAsync(ws, 0, 18432 * sizeof(float), stream);    // csp + b_glob + wsum

    const void* src = (const void*)P;
    void (*fp)(const void*, float*, float*) = ssk_iter<false>;
    void* args[] = { (void*)&src, (void*)&csp, (void*)&b_glob };
    hipLaunchCooperativeKernel((void*)fp, dim3(IT_BLOCKS), dim3(IT_THREADS),
                               args, 0, stream);

    ssk_finalize_kernel<<<dim3(FN_BLOCKS), dim3(FN_THREADS), 0, stream>>>(
        P, b_glob, out, wsum, loss_part);
    ssk_finish_kernel<<<dim3(1), dim3(1024), 0, stream>>>(wsum, loss_part, out);
  }
}

// Round 13
// 47226.138 us; speedup vs baseline: 5.8492x; 1.0876x over previous
//
#include <hip/hip_runtime.h>
#include <hip/hip_cooperative_groups.h>

constexpr int   NROWS = 65536;
constexpr int   NK    = 1024;
constexpr float PAv   = 1.0f / 65536.0f;
constexpr float PBv   = 1.0f / 1024.0f;
constexpr float FI    = 1.0f / 1.1f;          // GAMMA/(GAMMA+eps)
constexpr float NEG_INV_EPS = -10.0f;         // -1/eps
constexpr float STOPERR2 = 1e-12f;            // (1e-6)^2 on squared 2-norm
constexpr int   MAXIT = 1000;
constexpr float INVS  = 1.0f / 65535.0f;      // u16 fixed-point decode scale

// ---------------- Q conversion: P f32 -> Q u16 fixed-point (proven r11) ----
__global__ __launch_bounds__(256)
void q_conv_kernel(const float* __restrict__ P, uint4* __restrict__ Qb)
{
  const size_t total8 = (size_t)NROWS * NK / 8;
  for (size_t i = (size_t)blockIdx.x * blockDim.x + threadIdx.x; i < total8;
       i += (size_t)gridDim.x * blockDim.x) {
    const float4* p4 = reinterpret_cast<const float4*>(P) + 2 * i;
    float4 a = p4[0], b = p4[1];
    unsigned int u0 = __float2uint_rn(__expf(a.x * NEG_INV_EPS) * 65535.0f);
    unsigned int u1 = __float2uint_rn(__expf(a.y * NEG_INV_EPS) * 65535.0f);
    unsigned int u2 = __float2uint_rn(__expf(a.z * NEG_INV_EPS) * 65535.0f);
    unsigned int u3 = __float2uint_rn(__expf(a.w * NEG_INV_EPS) * 65535.0f);
    unsigned int u4 = __float2uint_rn(__expf(b.x * NEG_INV_EPS) * 65535.0f);
    unsigned int u5 = __float2uint_rn(__expf(b.y * NEG_INV_EPS) * 65535.0f);
    unsigned int u6 = __float2uint_rn(__expf(b.z * NEG_INV_EPS) * 65535.0f);
    unsigned int u7 = __float2uint_rn(__expf(b.w * NEG_INV_EPS) * 65535.0f);
    uint4 o;
    o.x = u0 | (u1 << 16);
    o.y = u2 | (u3 << 16);
    o.z = u4 | (u5 << 16);
    o.w = u6 | (u7 << 16);
    Qb[i] = o;
  }
}

// ---------------- cooperative Sinkhorn iteration (r11 + fast barrier) ------
// All cross-block state moves through MALL-coherent scoped atomics, so the
// barrier needs NO acquire (= no L2 invalidate) anywhere:
//   writes:  column sums via atomicAdd (device scope), slot-zero via
//            agent-relaxed atomic stores
//   barrier: per-wave RELEASE fence (s_waitcnt vmcnt(0) -> all prior writes
//            AND reads drained) -> relaxed fetch_add -> RELAXED spin+sleep
//   reads:   Phase B sums via agent-relaxed atomic loads (bypass L2)
// r6's regression was an ACQUIRE in the poll loop (L2 invalidate per poll,
// FETCH +23%); this design has zero acquire operations.
constexpr int IT_BLOCKS  = 256;
constexpr int IT_THREADS = 512;
constexpr int IT_WAVES   = IT_THREADS / 64;                 // 8
constexpr int IT_RPW     = NROWS / (IT_BLOCKS * IT_WAVES);  // 32 rows per wave
constexpr int NGRP       = 4;

template<bool U16>
__global__ __launch_bounds__(IT_THREADS, 2)
void ssk_iter(const void* __restrict__ src, float* __restrict__ csp /*[4][NGRP][NK]*/,
              unsigned int* __restrict__ bar, float* __restrict__ b_out)
{
  __shared__ float b_lds[NK];
  __shared__ float wave_cs[IT_WAVES][NK];   // 32 KiB
  __shared__ float redsh[IT_WAVES];
  __shared__ float err_sh;

  const int tid  = threadIdx.x;
  const int wave = tid >> 6;
  const int lane = tid & 63;
  const int bid  = blockIdx.x;
  const int grp  = bid & (NGRP - 1);
  const int row0 = (bid * IT_WAVES + wave) * IT_RPW;

  b_lds[tid] = PBv; b_lds[tid + 512] = PBv;   // b0 = 1/K
  __syncthreads();

  int it = 0;
  for (;;) {
    float* __restrict__ cs_cur = csp + (size_t)(it & 3) * (NGRP * NK);
    // slice-zero slot (it+2)&3 via agent-relaxed atomic stores (MALL-direct).
    // Ring audit: that slot's last readers (Phase B, iter it-2) drained their
    // loads before their release fence at barrier-arrive #(it-1); we observed
    // counter==target(it-1) before entering iter it -> zero lands after.
    if (tid < 4 * NGRP) {
      float* z = csp + (size_t)((it + 2) & 3) * (NGRP * NK);
      __hip_atomic_store(&z[(tid >> 2) * NK + bid * 4 + (tid & 3)], 0.0f,
                         __ATOMIC_RELAXED, __HIP_MEMORY_SCOPE_AGENT);
    }

    // lane's 16 columns: 256*k + 4*lane + j  (proven layout, 0 LDS conflicts)
    float bb[16];
    #pragma unroll
    for (int k = 0; k < 4; ++k)
      #pragma unroll
      for (int j = 0; j < 4; ++j)
        bb[4 * k + j] = b_lds[256 * k + 4 * lane + j];

    float acc[16];
    #pragma unroll
    for (int t = 0; t < 16; ++t) acc[t] = 0.0f;

    for (int r = 0; r < IT_RPW; r += 2) {     // 2-row batch (r5/r11-proven)
      float4 va[4], vb[4];
      if constexpr (U16) {
        const uint2* rA = reinterpret_cast<const uint2*>(src)
                        + (size_t)(row0 + r) * (NK / 4);
        const uint2* rB = rA + (NK / 4);
        uint2 ua[4], ub[4];
        #pragma unroll
        for (int k = 0; k < 4; ++k) { ua[k] = rA[(k << 6) + lane]; ub[k] = rB[(k << 6) + lane]; }
        #pragma unroll
        for (int k = 0; k < 4; ++k) {         // u16x4 -> f32x4 (no exp!)
          va[k].x = (float)(ua[k].x & 0xffffu) * INVS;
          va[k].y = (float)(ua[k].x >> 16)     * INVS;
          va[k].z = (float)(ua[k].y & 0xffffu) * INVS;
          va[k].w = (float)(ua[k].y >> 16)     * INVS;
          vb[k].x = (float)(ub[k].x & 0xffffu) * INVS;
          vb[k].y = (float)(ub[k].x >> 16)     * INVS;
          vb[k].z = (float)(ub[k].y & 0xffffu) * INVS;
          vb[k].w = (float)(ub[k].y >> 16)     * INVS;
        }
      } else {
        const float4* rpA = reinterpret_cast<const float4*>(src) + (size_t)(row0 + r)     * (NK / 4);
        const float4* rpB = reinterpret_cast<const float4*>(src) + (size_t)(row0 + r + 1) * (NK / 4);
        #pragma unroll
        for (int k = 0; k < 4; ++k) { va[k] = rpA[(k << 6) + lane]; vb[k] = rpB[(k << 6) + lane]; }
        #pragma unroll
        for (int k = 0; k < 4; ++k) {
          va[k].x = __expf(va[k].x * NEG_INV_EPS);
          va[k].y = __expf(va[k].y * NEG_INV_EPS);
          va[k].z = __expf(va[k].z * NEG_INV_EPS);
          va[k].w = __expf(va[k].w * NEG_INV_EPS);
          vb[k].x = __expf(vb[k].x * NEG_INV_EPS);
          vb[k].y = __expf(vb[k].y * NEG_INV_EPS);
          vb[k].z = __expf(vb[k].z * NEG_INV_EPS);
          vb[k].w = __expf(vb[k].w * NEG_INV_EPS);
        }
      }
      float dA = 0.f, dB = 0.f;
      #pragma unroll
      for (int k = 0; k < 4; ++k) {
        dA = fmaf(va[k].x, bb[4*k+0], dA);
        dA = fmaf(va[k].y, bb[4*k+1], dA);
        dA = fmaf(va[k].z, bb[4*k+2], dA);
        dA = fmaf(va[k].w, bb[4*k+3], dA);
        dB = fmaf(vb[k].x, bb[4*k+0], dB);
        dB = fmaf(vb[k].y, bb[4*k+1], dB);
        dB = fmaf(vb[k].z, bb[4*k+2], dB);
        dB = fmaf(vb[k].w, bb[4*k+3], dB);
      }
      #pragma unroll
      for (int off = 32; off; off >>= 1) {
        dA += __shfl_xor(dA, off);
        dB += __shfl_xor(dB, off);
      }
      const float aA = PAv / fmaxf(dA, 1e-12f);
      const float aB = PAv / fmaxf(dB, 1e-12f);
      #pragma unroll
      for (int k = 0; k < 4; ++k) {
        acc[4*k+0] = fmaf(aA, va[k].x, acc[4*k+0]);
        acc[4*k+1] = fmaf(aA, va[k].y, acc[4*k+1]);
        acc[4*k+2] = fmaf(aA, va[k].z, acc[4*k+2]);
        acc[4*k+3] = fmaf(aA, va[k].w, acc[4*k+3]);
        acc[4*k+0] = fmaf(aB, vb[k].x, acc[4*k+0]);
        acc[4*k+1] = fmaf(aB, vb[k].y, acc[4*k+1]);
        acc[4*k+2] = fmaf(aB, vb[k].z, acc[4*k+2]);
        acc[4*k+3] = fmaf(aB, vb[k].w, acc[4*k+3]);
      }
    }

    // block-level column reduction, one atomic per column per block (NGRP split)
    #pragma unroll
    for (int k = 0; k < 4; ++k)
      #pragma unroll
      for (int j = 0; j < 4; ++j)
        wave_cs[wave][256 * k + 4 * lane + j] = acc[4 * k + j];
    __syncthreads();
    #pragma unroll
    for (int h = 0; h < 2; ++h) {
      const int c = tid + 512 * h;
      float s = 0.f;
      #pragma unroll
      for (int w = 0; w < IT_WAVES; ++w) s += wave_cs[w][c];
      atomicAdd(&cs_cur[grp * NK + c], s);
    }

    // ---- minimal grid barrier: release + relaxed counter + relaxed spin ----
    // Release fence per wave: s_waitcnt drains this wave's atomics/stores
    // (and any outstanding loads) before the arrive is visible. No acquire:
    // Phase B reads go MALL-direct below.
    __builtin_amdgcn_fence(__ATOMIC_RELEASE, "agent");
    __syncthreads();                     // all waves of the block fenced
    if (tid == 0) {
      __hip_atomic_fetch_add(bar, 1u, __ATOMIC_RELAXED, __HIP_MEMORY_SCOPE_AGENT);
      const unsigned int tgt = (unsigned int)(it + 1) * (unsigned int)IT_BLOCKS;
      while (__hip_atomic_load(bar, __ATOMIC_RELAXED, __HIP_MEMORY_SCOPE_AGENT) < tgt)
        __builtin_amdgcn_s_sleep(8);
    }
    __syncthreads();
    asm volatile("" ::: "memory");       // compiler-only: no hoisting above spin

    // Phase B: every block redundantly (bit-identically) computes b_new + err.
    // cs reads are agent-relaxed atomic loads (MALL-direct; fixed group order
    // -> identical FP sums in every block).
    float c0 = 0.f, c1 = 0.f;
    #pragma unroll
    for (int g = 0; g < NGRP; ++g) {
      c0 += __hip_atomic_load(&cs_cur[g * NK + tid], __ATOMIC_RELAXED,
                              __HIP_MEMORY_SCOPE_AGENT);
      c1 += __hip_atomic_load(&cs_cur[g * NK + tid + 512], __ATOMIC_RELAXED,
                              __HIP_MEMORY_SCOPE_AGENT);
    }
    const float bn0 = powf(PBv / fmaxf(c0, 1e-12f), FI);
    const float bn1 = powf(PBv / fmaxf(c1, 1e-12f), FI);
    const float e0 = bn0 - b_lds[tid], e1 = bn1 - b_lds[tid + 512];
    float sq = e0 * e0 + e1 * e1;
    #pragma unroll
    for (int off = 32; off; off >>= 1) sq += __shfl_xor(sq, off);
    if (lane == 0) redsh[wave] = sq;
    __syncthreads();
    if (tid == 0) {
      float s = 0.f;
      #pragma unroll
      for (int w = 0; w < IT_WAVES; ++w) s += redsh[w];
      err_sh = s;
    }
    b_lds[tid] = bn0; b_lds[tid + 512] = bn1;  // own-index write
    ++it;
    __syncthreads();     // publishes err_sh and b_lds
    if (err_sh <= STOPERR2 || it >= MAXIT) break;   // uniform exit (bit-identical)
  }

  if (blockIdx.x == 0) { b_out[tid] = b_lds[tid]; b_out[tid + 512] = b_lds[tid + 512]; }
}

// ---------------- finalize: OT_plan + partial reductions (proven) ----------
constexpr int FN_BLOCKS  = 2048;
constexpr int FN_THREADS = 256;
constexpr int FN_WAVES   = FN_THREADS / 64;                  // 4
constexpr int FN_RPW     = NROWS / (FN_BLOCKS * FN_WAVES);   // 8

__global__ __launch_bounds__(FN_THREADS)
void ssk_finalize_kernel(const float* __restrict__ P, const float* __restrict__ b_glob,
                         float* __restrict__ out, float* __restrict__ wsum,
                         float* __restrict__ loss_part)
{
  __shared__ float b_sh[NK];
  __shared__ float wave_w[FN_WAVES][NK];
  __shared__ float red[FN_WAVES];

  const int tid  = threadIdx.x;
  const int wave = tid >> 6;
  const int lane = tid & 63;

  #pragma unroll
  for (int i = 0; i < 4; ++i) b_sh[tid + 256 * i] = b_glob[tid + 256 * i];
  __syncthreads();

  float bb[16];
  #pragma unroll
  for (int k = 0; k < 4; ++k)
    #pragma unroll
    for (int j = 0; j < 4; ++j)
      bb[4 * k + j] = b_sh[256 * k + 4 * lane + j];

  float wacc[16];
  #pragma unroll
  for (int t = 0; t < 16; ++t) wacc[t] = 0.0f;
  float lacc = 0.0f;

  const int row0 = (blockIdx.x * FN_WAVES + wave) * FN_RPW;
  float4* out4 = reinterpret_cast<float4*>(out);

  for (int r = 0; r < FN_RPW; ++r) {
    const size_t row = (size_t)(row0 + r);
    const float4* rp = reinterpret_cast<const float4*>(P) + row * (NK / 4);
    float4 pv[4];
    float Q[16];
    float dot = 0.0f;
    #pragma unroll
    for (int k = 0; k < 4; ++k) {
      pv[k] = rp[(k << 6) + lane];
      Q[4*k+0] = __expf(pv[k].x * NEG_INV_EPS);
      Q[4*k+1] = __expf(pv[k].y * NEG_INV_EPS);
      Q[4*k+2] = __expf(pv[k].z * NEG_INV_EPS);
      Q[4*k+3] = __expf(pv[k].w * NEG_INV_EPS);
      dot = fmaf(Q[4*k+0], bb[4*k+0], dot);
      dot = fmaf(Q[4*k+1], bb[4*k+1], dot);
      dot = fmaf(Q[4*k+2], bb[4*k+2], dot);
      dot = fmaf(Q[4*k+3], bb[4*k+3], dot);
    }
    #pragma unroll
    for (int off = 32; off; off >>= 1) dot += __shfl_xor(dot, off);
    const float s = 1.0f / fmaxf(dot, 1e-12f);    // N * a_i  (N*Pa = 1)
    #pragma unroll
    for (int k = 0; k < 4; ++k) {
      float4 o;
      o.x = s * Q[4*k+0] * bb[4*k+0];
      o.y = s * Q[4*k+1] * bb[4*k+1];
      o.z = s * Q[4*k+2] * bb[4*k+2];
      o.w = s * Q[4*k+3] * bb[4*k+3];
      out4[row * (NK / 4) + (k << 6) + lane] = o;
      lacc = fmaf(o.x, pv[k].x, lacc);
      lacc = fmaf(o.y, pv[k].y, lacc);
      lacc = fmaf(o.z, pv[k].z, lacc);
      lacc = fmaf(o.w, pv[k].w, lacc);
      wacc[4*k+0] += o.x; wacc[4*k+1] += o.y; wacc[4*k+2] += o.z; wacc[4*k+3] += o.w;
    }
  }

  #pragma unroll
  for (int k = 0; k < 4; ++k)
    #pragma unroll
    for (int j = 0; j < 4; ++j)
      wave_w[wave][256 * k + 4 * lane + j] = wacc[4 * k + j];
  __syncthreads();
  #pragma unroll
  for (int i = 0; i < 4; ++i) {
    const int c = tid + 256 * i;
    float s2 = wave_w[0][c] + wave_w[1][c] + wave_w[2][c] + wave_w[3][c];
    atomicAdd(&wsum[c], s2);
  }

  #pragma unroll
  for (int off = 32; off; off >>= 1) lacc += __shfl_xor(lacc, off);
  if (lane == 0) red[wave] = lacc;
  __syncthreads();
  if (tid == 0) loss_part[blockIdx.x] = red[0] + red[1] + red[2] + red[3];
}

// ---------------- finish: scalars ----------------
__device__ __forceinline__ float ssk_block_sum_1024(float v, float* red, int wave, int lane)
{
  #pragma unroll
  for (int off = 32; off; off >>= 1) v += __shfl_xor(v, off);
  __syncthreads();
  if (lane == 0) red[wave] = v;
  __syncthreads();
  float t = 0.0f;
  #pragma unroll
  for (int w = 0; w < 16; ++w) t += red[w];
  return t;
}

__global__ __launch_bounds__(1024)
void ssk_finish_kernel(const float* __restrict__ wsum, const float* __restrict__ loss_part,
                       float* __restrict__ out)
{
  __shared__ float red[16];
  const int tid = threadIdx.x, wave = tid >> 6, lane = tid & 63;

  float l  = loss_part[tid] + loss_part[tid + 1024];
  float lt = ssk_block_sum_1024(l, red, wave, lane);

  float wm = wsum[tid] * (1.0f / (float)NROWS);
  float sw = ssk_block_sum_1024(wm, red, wave, lane);
  float wn = wm / (sw + 1e-8f);
  float v  = PBv * (logf(PBv) - logf(wn + 1e-7f));
  float rg = ssk_block_sum_1024(v, red, wave, lane);

  if (tid == 0) {
    out[(size_t)NROWS * NK]     = lt / (float)NROWS;  // ot_loss
    out[(size_t)NROWS * NK + 1] = rg;                 // reg
  }
}

// ---------------- launch ----------------
extern "C" void kernel_launch(void* const* d_in, const int* in_sizes, int n_in,
                              void* d_out, int out_size, void* d_ws, size_t ws_size,
                              hipStream_t stream)
{
  const float* P = (const float*)d_in[0];
  float* out = (float*)d_out;
  float* ws  = (float*)d_ws;

  float*        csp = ws;                              // [4][NGRP][1024] = 64 KB
  unsigned int* bar = (unsigned int*)(ws + 16384);     // own region (64 B)
  const size_t  QF  = (size_t)NROWS * NK / 2;          // u16 cache in float units
  const size_t need = (16448 + QF + 1024 + 1024 + 2048) * sizeof(float);

  if (ws_size >= need) {
    unsigned short* qbuf = (unsigned short*)(ws + 16448);
    float* b_glob    = ws + 16448 + QF;
    float* wsum      = b_glob + 1024;
    float* loss_part = b_glob + 2048;

    hipMemsetAsync(ws, 0, 16448 * sizeof(float), stream);    // csp + bar
    hipMemsetAsync(b_glob, 0, 2048 * sizeof(float), stream); // b_glob + wsum

    q_conv_kernel<<<dim3(2048), dim3(256), 0, stream>>>(P, (uint4*)qbuf);

    const void* src = qbuf;
    void (*fp)(const void*, float*, unsigned int*, float*) = ssk_iter<true>;
    void* args[] = { (void*)&src, (void*)&csp, (void*)&bar, (void*)&b_glob };
    hipLaunchCooperativeKernel((void*)fp, dim3(IT_BLOCKS), dim3(IT_THREADS),
                               args, 0, stream);

    ssk_finalize_kernel<<<dim3(FN_BLOCKS), dim3(FN_THREADS), 0, stream>>>(
        P, b_glob, out, wsum, loss_part);
    ssk_finish_kernel<<<dim3(1), dim3(1024), 0, stream>>>(wsum, loss_part, out);
  } else {
    float* b_glob    = ws + 16448;
    float* wsum      = b_glob + 1024;
    float* loss_part = b_glob + 2048;

    hipMemsetAsync(ws, 0, (16448 + 2048) * sizeof(float), stream);

    const void* src = (const void*)P;
    void (*fp)(const void*, float*, unsigned int*, float*) = ssk_iter<false>;
    void* args[] = { (void*)&src, (void*)&csp, (void*)&bar, (void*)&b_glob };
    hipLaunchCooperativeKernel((void*)fp, dim3(IT_BLOCKS), dim3(IT_THREADS),
                               args, 0, stream);

    ssk_finalize_kernel<<<dim3(FN_BLOCKS), dim3(FN_THREADS), 0, stream>>>(
        P, b_glob, out, wsum, loss_part);
    ssk_finish_kernel<<<dim3(1), dim3(1024), 0, stream>>>(wsum, loss_part, out);
  }
}

// Round 14
// 11518.151 us; speedup vs baseline: 23.9825x; 4.1001x over previous
//
#include <hip/hip_runtime.h>
#include <hip/hip_cooperative_groups.h>

constexpr int   NROWS = 65536;
constexpr int   NK    = 1024;
constexpr float PAv   = 1.0f / 65536.0f;
constexpr float PBv   = 1.0f / 1024.0f;
constexpr float FI    = 1.0f / 1.1f;          // GAMMA/(GAMMA+eps)
constexpr float NEG_INV_EPS = -10.0f;         // -1/eps
constexpr float STOPERR2 = 1e-12f;            // (1e-6)^2 on squared 2-norm
constexpr int   MAXIT = 1000;
constexpr float INVS  = 1.0f / 65535.0f;      // u16 fixed-point decode scale

// ---------------- Q conversion: P f32 -> Q u16 fixed-point (proven r11) ----
__global__ __launch_bounds__(256)
void q_conv_kernel(const float* __restrict__ P, uint4* __restrict__ Qb)
{
  const size_t total8 = (size_t)NROWS * NK / 8;
  for (size_t i = (size_t)blockIdx.x * blockDim.x + threadIdx.x; i < total8;
       i += (size_t)gridDim.x * blockDim.x) {
    const float4* p4 = reinterpret_cast<const float4*>(P) + 2 * i;
    float4 a = p4[0], b = p4[1];
    unsigned int u0 = __float2uint_rn(__expf(a.x * NEG_INV_EPS) * 65535.0f);
    unsigned int u1 = __float2uint_rn(__expf(a.y * NEG_INV_EPS) * 65535.0f);
    unsigned int u2 = __float2uint_rn(__expf(a.z * NEG_INV_EPS) * 65535.0f);
    unsigned int u3 = __float2uint_rn(__expf(a.w * NEG_INV_EPS) * 65535.0f);
    unsigned int u4 = __float2uint_rn(__expf(b.x * NEG_INV_EPS) * 65535.0f);
    unsigned int u5 = __float2uint_rn(__expf(b.y * NEG_INV_EPS) * 65535.0f);
    unsigned int u6 = __float2uint_rn(__expf(b.z * NEG_INV_EPS) * 65535.0f);
    unsigned int u7 = __float2uint_rn(__expf(b.w * NEG_INV_EPS) * 65535.0f);
    uint4 o;
    o.x = u0 | (u1 << 16);
    o.y = u2 | (u3 << 16);
    o.z = u4 | (u5 << 16);
    o.w = u6 | (u7 << 16);
    Qb[i] = o;
  }
}

// ---------------- packed-f32-pair helpers ----------------
__device__ __forceinline__ unsigned long long pack2f(float a, float b) {
  return (unsigned long long)__float_as_uint(a) |
         ((unsigned long long)__float_as_uint(b) << 32);
}
__device__ __forceinline__ float lo2f(unsigned long long u) {
  return __uint_as_float((unsigned int)(u & 0xffffffffull));
}
__device__ __forceinline__ float hi2f(unsigned long long u) {
  return __uint_as_float((unsigned int)(u >> 32));
}

// ---------------- cooperative Sinkhorn iteration (zero-RMW design) --------
// r13 post-mortem: the ~70 us/iter fixed cost tracks device-scope RMW count
// (262K atomicAdd/iter; r10's 2.1M cost ~8x). This round has ZERO RMW in the
// data path: block partials are packed-8B relaxed agent STORES; the owned-
// column reduce is relaxed agent LOADS + shuffle tree; b is broadcast the
// same way. Barriers: 16 split counters (16 blocks each) so even the arrive
// RMW chain is 16-deep, not 256-deep.
constexpr int IT_BLOCKS  = 256;
constexpr int IT_THREADS = 512;
constexpr int IT_WAVES   = IT_THREADS / 64;                 // 8
constexpr int IT_RPW     = NROWS / (IT_BLOCKS * IT_WAVES);  // 32 rows per wave
constexpr int NCTR       = 16;
constexpr int CTR_STRIDE = 64;                              // 256 B spacing

template<bool U16>
__global__ __launch_bounds__(IT_THREADS, 2)
void ssk_iter(const void* __restrict__ src,
              unsigned long long* __restrict__ partial /*[256][512] packed*/,
              unsigned long long* __restrict__ bvec    /*[512] packed*/,
              unsigned int* __restrict__ ctrs          /*[16] spaced*/,
              float* __restrict__ b_out)
{
  __shared__ float b_lds[NK];
  __shared__ float wave_cs[IT_WAVES][NK];   // 32 KiB
  __shared__ float redsh[IT_WAVES];
  __shared__ float fred[4][4];              // B1 cross-wave float4 sums
  __shared__ float err_sh;

  const int tid  = threadIdx.x;
  const int wave = tid >> 6;
  const int lane = tid & 63;
  const int bid  = blockIdx.x;
  const int row0 = (bid * IT_WAVES + wave) * IT_RPW;

  b_lds[tid] = PBv; b_lds[tid + 512] = PBv;   // b0 = 1/K
  __syncthreads();

  int it = 0;
  int ph = 0;                                 // barrier phase counter
  for (;;) {
    // ---------------- stream phase (r13-proven) ----------------
    float bb[16];
    #pragma unroll
    for (int k = 0; k < 4; ++k)
      #pragma unroll
      for (int j = 0; j < 4; ++j)
        bb[4 * k + j] = b_lds[256 * k + 4 * lane + j];

    float acc[16];
    #pragma unroll
    for (int t = 0; t < 16; ++t) acc[t] = 0.0f;

    for (int r = 0; r < IT_RPW; r += 2) {     // 2-row batch
      float4 va[4], vb[4];
      if constexpr (U16) {
        const uint2* rA = reinterpret_cast<const uint2*>(src)
                        + (size_t)(row0 + r) * (NK / 4);
        const uint2* rB = rA + (NK / 4);
        uint2 ua[4], ub[4];
        #pragma unroll
        for (int k = 0; k < 4; ++k) { ua[k] = rA[(k << 6) + lane]; ub[k] = rB[(k << 6) + lane]; }
        #pragma unroll
        for (int k = 0; k < 4; ++k) {
          va[k].x = (float)(ua[k].x & 0xffffu) * INVS;
          va[k].y = (float)(ua[k].x >> 16)     * INVS;
          va[k].z = (float)(ua[k].y & 0xffffu) * INVS;
          va[k].w = (float)(ua[k].y >> 16)     * INVS;
          vb[k].x = (float)(ub[k].x & 0xffffu) * INVS;
          vb[k].y = (float)(ub[k].x >> 16)     * INVS;
          vb[k].z = (float)(ub[k].y & 0xffffu) * INVS;
          vb[k].w = (float)(ub[k].y >> 16)     * INVS;
        }
      } else {
        const float4* rpA = reinterpret_cast<const float4*>(src) + (size_t)(row0 + r)     * (NK / 4);
        const float4* rpB = reinterpret_cast<const float4*>(src) + (size_t)(row0 + r + 1) * (NK / 4);
        #pragma unroll
        for (int k = 0; k < 4; ++k) { va[k] = rpA[(k << 6) + lane]; vb[k] = rpB[(k << 6) + lane]; }
        #pragma unroll
        for (int k = 0; k < 4; ++k) {
          va[k].x = __expf(va[k].x * NEG_INV_EPS);
          va[k].y = __expf(va[k].y * NEG_INV_EPS);
          va[k].z = __expf(va[k].z * NEG_INV_EPS);
          va[k].w = __expf(va[k].w * NEG_INV_EPS);
          vb[k].x = __expf(vb[k].x * NEG_INV_EPS);
          vb[k].y = __expf(vb[k].y * NEG_INV_EPS);
          vb[k].z = __expf(vb[k].z * NEG_INV_EPS);
          vb[k].w = __expf(vb[k].w * NEG_INV_EPS);
        }
      }
      float dA = 0.f, dB = 0.f;
      #pragma unroll
      for (int k = 0; k < 4; ++k) {
        dA = fmaf(va[k].x, bb[4*k+0], dA);
        dA = fmaf(va[k].y, bb[4*k+1], dA);
        dA = fmaf(va[k].z, bb[4*k+2], dA);
        dA = fmaf(va[k].w, bb[4*k+3], dA);
        dB = fmaf(vb[k].x, bb[4*k+0], dB);
        dB = fmaf(vb[k].y, bb[4*k+1], dB);
        dB = fmaf(vb[k].z, bb[4*k+2], dB);
        dB = fmaf(vb[k].w, bb[4*k+3], dB);
      }
      #pragma unroll
      for (int off = 32; off; off >>= 1) {
        dA += __shfl_xor(dA, off);
        dB += __shfl_xor(dB, off);
      }
      const float aA = PAv / fmaxf(dA, 1e-12f);
      const float aB = PAv / fmaxf(dB, 1e-12f);
      #pragma unroll
      for (int k = 0; k < 4; ++k) {
        acc[4*k+0] = fmaf(aA, va[k].x, acc[4*k+0]);
        acc[4*k+1] = fmaf(aA, va[k].y, acc[4*k+1]);
        acc[4*k+2] = fmaf(aA, va[k].z, acc[4*k+2]);
        acc[4*k+3] = fmaf(aA, va[k].w, acc[4*k+3]);
        acc[4*k+0] = fmaf(aB, vb[k].x, acc[4*k+0]);
        acc[4*k+1] = fmaf(aB, vb[k].y, acc[4*k+1]);
        acc[4*k+2] = fmaf(aB, vb[k].z, acc[4*k+2]);
        acc[4*k+3] = fmaf(aB, vb[k].w, acc[4*k+3]);
      }
    }

    // block-level column reduction in LDS (proven layout, 0 conflicts)
    #pragma unroll
    for (int k = 0; k < 4; ++k)
      #pragma unroll
      for (int j = 0; j < 4; ++j)
        wave_cs[wave][256 * k + 4 * lane + j] = acc[4 * k + j];
    __syncthreads();

    // partial write: cols 2*tid, 2*tid+1 packed into one 8B relaxed store.
    // NO RMW. partial[bid] is re-written next iteration only after barrier B
    // of this iteration (readers' release fences drained their loads first).
    {
      const int c0i = 2 * tid, c1i = 2 * tid + 1;
      float s0 = 0.f, s1 = 0.f;
      #pragma unroll
      for (int w = 0; w < IT_WAVES; ++w) { s0 += wave_cs[w][c0i]; s1 += wave_cs[w][c1i]; }
      __hip_atomic_store(&partial[bid * 512 + tid], pack2f(s0, s1),
                         __ATOMIC_RELAXED, __HIP_MEMORY_SCOPE_AGENT);
    }

    // ---------------- barrier A ----------------
    ++ph;
    __builtin_amdgcn_fence(__ATOMIC_RELEASE, "agent");   // drain stores (vmcnt)
    __syncthreads();
    if (tid == 0)
      __hip_atomic_fetch_add(&ctrs[(bid & (NCTR - 1)) * CTR_STRIDE], 1u,
                             __ATOMIC_RELAXED, __HIP_MEMORY_SCOPE_AGENT);
    if (tid < NCTR) {
      const unsigned int tgt = (unsigned int)ph * (IT_BLOCKS / NCTR);
      while (__hip_atomic_load(&ctrs[tid * CTR_STRIDE], __ATOMIC_RELAXED,
                               __HIP_MEMORY_SCOPE_AGENT) < tgt)
        __builtin_amdgcn_s_sleep(4);
    }
    __syncthreads();
    asm volatile("" ::: "memory");

    // ---------------- B1: reduce OWN 4 columns over 256 partials ----------
    // thread i<256 reads row i's 16B slice (2x8B relaxed loads), 4-wave
    // shuffle tree, thread 0 applies powf and publishes 2 packed b-values.
    if (tid < 256) {
      unsigned long long u0 = __hip_atomic_load(&partial[tid * 512 + 2 * bid],
                                                __ATOMIC_RELAXED, __HIP_MEMORY_SCOPE_AGENT);
      unsigned long long u1 = __hip_atomic_load(&partial[tid * 512 + 2 * bid + 1],
                                                __ATOMIC_RELAXED, __HIP_MEMORY_SCOPE_AGENT);
      float v0 = lo2f(u0), v1 = hi2f(u0), v2 = lo2f(u1), v3 = hi2f(u1);
      #pragma unroll
      for (int off = 32; off; off >>= 1) {
        v0 += __shfl_xor(v0, off);
        v1 += __shfl_xor(v1, off);
        v2 += __shfl_xor(v2, off);
        v3 += __shfl_xor(v3, off);
      }
      if (lane == 0) { fred[wave][0] = v0; fred[wave][1] = v1; fred[wave][2] = v2; fred[wave][3] = v3; }
    }
    __syncthreads();
    if (tid == 0) {
      float c0 = fred[0][0] + fred[1][0] + fred[2][0] + fred[3][0];
      float c1 = fred[0][1] + fred[1][1] + fred[2][1] + fred[3][1];
      float c2 = fred[0][2] + fred[1][2] + fred[2][2] + fred[3][2];
      float c3 = fred[0][3] + fred[1][3] + fred[2][3] + fred[3][3];
      const float b0 = powf(PBv / fmaxf(c0, 1e-12f), FI);
      const float b1 = powf(PBv / fmaxf(c1, 1e-12f), FI);
      const float b2 = powf(PBv / fmaxf(c2, 1e-12f), FI);
      const float b3 = powf(PBv / fmaxf(c3, 1e-12f), FI);
      __hip_atomic_store(&bvec[2 * bid],     pack2f(b0, b1),
                         __ATOMIC_RELAXED, __HIP_MEMORY_SCOPE_AGENT);
      __hip_atomic_store(&bvec[2 * bid + 1], pack2f(b2, b3),
                         __ATOMIC_RELAXED, __HIP_MEMORY_SCOPE_AGENT);
    }

    // ---------------- barrier B ----------------
    ++ph;
    __builtin_amdgcn_fence(__ATOMIC_RELEASE, "agent");
    __syncthreads();
    if (tid == 0)
      __hip_atomic_fetch_add(&ctrs[(bid & (NCTR - 1)) * CTR_STRIDE], 1u,
                             __ATOMIC_RELAXED, __HIP_MEMORY_SCOPE_AGENT);
    if (tid < NCTR) {
      const unsigned int tgt = (unsigned int)ph * (IT_BLOCKS / NCTR);
      while (__hip_atomic_load(&ctrs[tid * CTR_STRIDE], __ATOMIC_RELAXED,
                               __HIP_MEMORY_SCOPE_AGENT) < tgt)
        __builtin_amdgcn_s_sleep(4);
    }
    __syncthreads();
    asm volatile("" ::: "memory");

    // ---------------- B2: broadcast b, err, update ----------------
    // every block reads identical bvec -> bit-identical err and b_lds.
    const unsigned long long ub = __hip_atomic_load(&bvec[tid], __ATOMIC_RELAXED,
                                                    __HIP_MEMORY_SCOPE_AGENT);
    const float bn0 = lo2f(ub), bn1 = hi2f(ub);
    const float o0 = b_lds[2 * tid], o1 = b_lds[2 * tid + 1];
    const float e0 = bn0 - o0, e1 = bn1 - o1;
    float sq = e0 * e0 + e1 * e1;
    #pragma unroll
    for (int off = 32; off; off >>= 1) sq += __shfl_xor(sq, off);
    if (lane == 0) redsh[wave] = sq;
    __syncthreads();
    if (tid == 0) {
      float s = 0.f;
      #pragma unroll
      for (int w = 0; w < IT_WAVES; ++w) s += redsh[w];
      err_sh = s;
    }
    b_lds[2 * tid] = bn0; b_lds[2 * tid + 1] = bn1;  // own-index write
    ++it;
    __syncthreads();     // publishes err_sh and b_lds
    if (err_sh <= STOPERR2 || it >= MAXIT) break;    // uniform exit
  }

  if (blockIdx.x == 0) { b_out[tid] = b_lds[tid]; b_out[tid + 512] = b_lds[tid + 512]; }
}

// ---------------- finalize: OT_plan + partial reductions (proven) ----------
constexpr int FN_BLOCKS  = 2048;
constexpr int FN_THREADS = 256;
constexpr int FN_WAVES   = FN_THREADS / 64;                  // 4
constexpr int FN_RPW     = NROWS / (FN_BLOCKS * FN_WAVES);   // 8

__global__ __launch_bounds__(FN_THREADS)
void ssk_finalize_kernel(const float* __restrict__ P, const float* __restrict__ b_glob,
                         float* __restrict__ out, float* __restrict__ wsum,
                         float* __restrict__ loss_part)
{
  __shared__ float b_sh[NK];
  __shared__ float wave_w[FN_WAVES][NK];
  __shared__ float red[FN_WAVES];

  const int tid  = threadIdx.x;
  const int wave = tid >> 6;
  const int lane = tid & 63;

  #pragma unroll
  for (int i = 0; i < 4; ++i) b_sh[tid + 256 * i] = b_glob[tid + 256 * i];
  __syncthreads();

  float bb[16];
  #pragma unroll
  for (int k = 0; k < 4; ++k)
    #pragma unroll
    for (int j = 0; j < 4; ++j)
      bb[4 * k + j] = b_sh[256 * k + 4 * lane + j];

  float wacc[16];
  #pragma unroll
  for (int t = 0; t < 16; ++t) wacc[t] = 0.0f;
  float lacc = 0.0f;

  const int row0 = (blockIdx.x * FN_WAVES + wave) * FN_RPW;
  float4* out4 = reinterpret_cast<float4*>(out);

  for (int r = 0; r < FN_RPW; ++r) {
    const size_t row = (size_t)(row0 + r);
    const float4* rp = reinterpret_cast<const float4*>(P) + row * (NK / 4);
    float4 pv[4];
    float Q[16];
    float dot = 0.0f;
    #pragma unroll
    for (int k = 0; k < 4; ++k) {
      pv[k] = rp[(k << 6) + lane];
      Q[4*k+0] = __expf(pv[k].x * NEG_INV_EPS);
      Q[4*k+1] = __expf(pv[k].y * NEG_INV_EPS);
      Q[4*k+2] = __expf(pv[k].z * NEG_INV_EPS);
      Q[4*k+3] = __expf(pv[k].w * NEG_INV_EPS);
      dot = fmaf(Q[4*k+0], bb[4*k+0], dot);
      dot = fmaf(Q[4*k+1], bb[4*k+1], dot);
      dot = fmaf(Q[4*k+2], bb[4*k+2], dot);
      dot = fmaf(Q[4*k+3], bb[4*k+3], dot);
    }
    #pragma unroll
    for (int off = 32; off; off >>= 1) dot += __shfl_xor(dot, off);
    const float s = 1.0f / fmaxf(dot, 1e-12f);    // N * a_i  (N*Pa = 1)
    #pragma unroll
    for (int k = 0; k < 4; ++k) {
      float4 o;
      o.x = s * Q[4*k+0] * bb[4*k+0];
      o.y = s * Q[4*k+1] * bb[4*k+1];
      o.z = s * Q[4*k+2] * bb[4*k+2];
      o.w = s * Q[4*k+3] * bb[4*k+3];
      out4[row * (NK / 4) + (k << 6) + lane] = o;
      lacc = fmaf(o.x, pv[k].x, lacc);
      lacc = fmaf(o.y, pv[k].y, lacc);
      lacc = fmaf(o.z, pv[k].z, lacc);
      lacc = fmaf(o.w, pv[k].w, lacc);
      wacc[4*k+0] += o.x; wacc[4*k+1] += o.y; wacc[4*k+2] += o.z; wacc[4*k+3] += o.w;
    }
  }

  #pragma unroll
  for (int k = 0; k < 4; ++k)
    #pragma unroll
    for (int j = 0; j < 4; ++j)
      wave_w[wave][256 * k + 4 * lane + j] = wacc[4 * k + j];
  __syncthreads();
  #pragma unroll
  for (int i = 0; i < 4; ++i) {
    const int c = tid + 256 * i;
    float s2 = wave_w[0][c] + wave_w[1][c] + wave_w[2][c] + wave_w[3][c];
    atomicAdd(&wsum[c], s2);
  }

  #pragma unroll
  for (int off = 32; off; off >>= 1) lacc += __shfl_xor(lacc, off);
  if (lane == 0) red[wave] = lacc;
  __syncthreads();
  if (tid == 0) loss_part[blockIdx.x] = red[0] + red[1] + red[2] + red[3];
}

// ---------------- finish: scalars ----------------
__device__ __forceinline__ float ssk_block_sum_1024(float v, float* red, int wave, int lane)
{
  #pragma unroll
  for (int off = 32; off; off >>= 1) v += __shfl_xor(v, off);
  __syncthreads();
  if (lane == 0) red[wave] = v;
  __syncthreads();
  float t = 0.0f;
  #pragma unroll
  for (int w = 0; w < 16; ++w) t += red[w];
  return t;
}

__global__ __launch_bounds__(1024)
void ssk_finish_kernel(const float* __restrict__ wsum, const float* __restrict__ loss_part,
                       float* __restrict__ out)
{
  __shared__ float red[16];
  const int tid = threadIdx.x, wave = tid >> 6, lane = tid & 63;

  float l  = loss_part[tid] + loss_part[tid + 1024];
  float lt = ssk_block_sum_1024(l, red, wave, lane);

  float wm = wsum[tid] * (1.0f / (float)NROWS);
  float sw = ssk_block_sum_1024(wm, red, wave, lane);
  float wn = wm / (sw + 1e-8f);
  float v  = PBv * (logf(PBv) - logf(wn + 1e-7f));
  float rg = ssk_block_sum_1024(v, red, wave, lane);

  if (tid == 0) {
    out[(size_t)NROWS * NK]     = lt / (float)NROWS;  // ot_loss
    out[(size_t)NROWS * NK + 1] = rg;                 // reg
  }
}

// ---------------- launch ----------------
extern "C" void kernel_launch(void* const* d_in, const int* in_sizes, int n_in,
                              void* d_out, int out_size, void* d_ws, size_t ws_size,
                              hipStream_t stream)
{
  const float* P = (const float*)d_in[0];
  float* out = (float*)d_out;
  float* ws  = (float*)d_ws;

  // partial lives in d_out's first 1 MiB (dead until finalize overwrites it)
  unsigned long long* partial = (unsigned long long*)d_out;
  unsigned long long* bvec    = (unsigned long long*)ws;     // [512] = 4 KB
  unsigned int*       ctrs    = (unsigned int*)(ws + 1024);  // 16 x 256 B spaced
  float* b_glob    = ws + 2048;
  float* wsum      = ws + 3072;
  float* loss_part = ws + 4096;      // [2048]

  const size_t QF   = (size_t)NROWS * NK / 2;   // u16 cache in float units
  const size_t need = (16384 + QF + 4096 + 2048) * sizeof(float);  // r11-accepted

  // zero bvec + ctrs + b_glob + wsum (deterministic across graph replays)
  hipMemsetAsync(ws, 0, 4096 * sizeof(float), stream);

  if (ws_size >= need) {
    unsigned short* qbuf = (unsigned short*)(ws + 16384);
    q_conv_kernel<<<dim3(2048), dim3(256), 0, stream>>>(P, (uint4*)qbuf);

    const void* src = qbuf;
    void (*fp)(const void*, unsigned long long*, unsigned long long*,
               unsigned int*, float*) = ssk_iter<true>;
    void* args[] = { (void*)&src, (void*)&partial, (void*)&bvec, (void*)&ctrs,
                     (void*)&b_glob };
    hipLaunchCooperativeKernel((void*)fp, dim3(IT_BLOCKS), dim3(IT_THREADS),
                               args, 0, stream);
  } else {
    const void* src = (const void*)P;
    void (*fp)(const void*, unsigned long long*, unsigned long long*,
               unsigned int*, float*) = ssk_iter<false>;
    void* args[] = { (void*)&src, (void*)&partial, (void*)&bvec, (void*)&ctrs,
                     (void*)&b_glob };
    hipLaunchCooperativeKernel((void*)fp, dim3(IT_BLOCKS), dim3(IT_THREADS),
                               args, 0, stream);
  }

  ssk_finalize_kernel<<<dim3(FN_BLOCKS), dim3(FN_THREADS), 0, stream>>>(
      P, b_glob, out, wsum, loss_part);
  ssk_finish_kernel<<<dim3(1), dim3(1024), 0, stream>>>(wsum, loss_part, out);
}